// Round 1
// baseline (143.842 us; speedup 1.0000x reference)
//
#include <hip/hip_runtime.h>

typedef __attribute__((ext_vector_type(8))) short short8v;
typedef __attribute__((ext_vector_type(4))) float f32x4;
typedef unsigned short u16;
typedef unsigned int u32;

#define MFMA __builtin_amdgcn_mfma_f32_16x16x32_bf16

// ---------- helpers ----------
__device__ __forceinline__ u16 f2b(float f) {
  u32 u = __float_as_uint(f);
  u = (u + 0x7FFFu + ((u >> 16) & 1u)) >> 16;
  return (u16)u;
}
__device__ __forceinline__ float b2f(u16 b) {
  return __uint_as_float(((u32)b) << 16);
}
__device__ __forceinline__ void g2l16(const void* g, void* l) {
  __builtin_amdgcn_global_load_lds(
      (const __attribute__((address_space(1))) unsigned int*)g,
      (__attribute__((address_space(3))) unsigned int*)l, 16, 0, 0);
}

// sizes
#define N_TOK 2048
#define DIM 1024
#define NH 16
#define HD 64

// workspace layout (bytes)
#define OFF_PERM 0
#define OFF_CNT 8192
#define OFF_XPB 16384
#define OFF_WT (OFF_XPB + 4194304)          // 16 MB: [tensor][expert][1024][1024] bf16, WT[n][k]
#define OFF_Q (OFF_WT + 16777216)
#define OFF_K (OFF_Q + 4194304)
#define OFF_V (OFF_K + 4194304)
#define OFF_VT (OFF_V + 4194304)            // [16][64][2048] bf16
#define OFF_AT (OFF_VT + 4194304)
#define OFF_O (OFF_AT + 4194304)            // f32 [2048][1024]

// ---------- prep: modality ids, stable partition perm, cnt0 ----------
__global__ __launch_bounds__(256) void prep_kernel(const void* __restrict__ masks,
                                                   int* __restrict__ perm,
                                                   int* __restrict__ cnt) {
  const int tid = threadIdx.x;
  __shared__ u32 red[256];
  __shared__ int scan[256];
  const u32* mw = (const u32*)masks;
  // detect storage: bool-bytes vs int32.  first 1024 words cover all 4096 bytes
  // in byte case; partition-complement guarantees a word > 1 there.
  u32 mx = 0;
  for (int i = tid; i < 1024; i += 256) { u32 v = mw[i]; mx = mx > v ? mx : v; }
  red[tid] = mx;
  __syncthreads();
  for (int off = 128; off; off >>= 1) {
    if (tid < off) red[tid] = red[tid] > red[tid + off] ? red[tid] : red[tid + off];
    __syncthreads();
  }
  const bool isbyte = red[0] > 1u;
  int md[8];
  int c0loc = 0;
  #pragma unroll
  for (int j = 0; j < 8; ++j) {
    const int n = tid * 8 + j;
    int m1;
    if (isbyte) m1 = ((const unsigned char*)masks)[N_TOK + n] != 0;
    else        m1 = mw[N_TOK + n] != 0;
    md[j] = m1;
    c0loc += (m1 == 0);
  }
  scan[tid] = c0loc;
  __syncthreads();
  for (int off = 1; off < 256; off <<= 1) {
    int v = (tid >= off) ? scan[tid - off] : 0;
    __syncthreads();
    scan[tid] += v;
    __syncthreads();
  }
  const int incl = scan[tid];
  const int total0 = scan[255];
  const int excl0 = incl - c0loc;
  int p0 = excl0;
  int p1 = total0 + (tid * 8 - excl0);
  #pragma unroll
  for (int j = 0; j < 8; ++j) {
    const int n = tid * 8 + j;
    if (!md[j]) perm[p0++] = n; else perm[p1++] = n;
  }
  if (tid == 0) cnt[0] = total0;
}

// ---------- gather + cast x -> xp bf16 ----------
__global__ __launch_bounds__(256) void gather_cast(const float* __restrict__ x,
                                                   const int* __restrict__ perm,
                                                   u16* __restrict__ xpb) {
  const int i = blockIdx.x;
  const int src = perm[i];
  const int tid = threadIdx.x;
  float4 v = ((const float4*)(x + (size_t)src * DIM))[tid];
  ushort4 o;
  o.x = f2b(v.x); o.y = f2b(v.y); o.z = f2b(v.z); o.w = f2b(v.w);
  ((ushort4*)(xpb + (size_t)i * DIM))[tid] = o;
}

// ---------- weight transpose-cast: W[k][n] f32 -> WT[n][k] bf16 ----------
__global__ __launch_bounds__(256) void wcast(const float* __restrict__ wq,
                                             const float* __restrict__ wk,
                                             const float* __restrict__ wv,
                                             const float* __restrict__ wo,
                                             u16* __restrict__ wT) {
  const int mat = blockIdx.z;               // tensor*2 + expert
  const int tensor = mat >> 1, expert = mat & 1;
  const float* src = (tensor == 0) ? wq : (tensor == 1) ? wk : (tensor == 2) ? wv : wo;
  src += (size_t)expert * (1 << 20);
  u16* dst = wT + ((size_t)mat << 20);
  const int k0 = blockIdx.x * 32, n0 = blockIdx.y * 32;
  const int tx = threadIdx.x, ty = threadIdx.y;
  __shared__ float t[32][33];
  #pragma unroll
  for (int r = 0; r < 4; ++r)
    t[ty + 8 * r][tx] = src[(size_t)(k0 + ty + 8 * r) * DIM + n0 + tx];
  __syncthreads();
  #pragma unroll
  for (int r = 0; r < 4; ++r)
    dst[(size_t)(n0 + ty + 8 * r) * DIM + k0 + tx] = f2b(t[tx][ty + 8 * r]);
}

// ---------- V transpose per head: v[n][h*64+d] -> vT[h][d][n] ----------
__global__ __launch_bounds__(256) void vtrans(const u16* __restrict__ v,
                                              u16* __restrict__ vT) {
  const int h = blockIdx.z;
  const int n0 = blockIdx.x * 32, d0 = blockIdx.y * 32;
  const int tx = threadIdx.x, ty = threadIdx.y;
  __shared__ u16 t[32][33];
  #pragma unroll
  for (int r = 0; r < 4; ++r)
    t[ty + 8 * r][tx] = v[(size_t)(n0 + ty + 8 * r) * DIM + h * HD + d0 + tx];
  __syncthreads();
  #pragma unroll
  for (int r = 0; r < 4; ++r)
    vT[(size_t)(h * HD + d0 + ty + 8 * r) * N_TOK + n0 + tx] = t[tx][ty + 8 * r];
}

// ---------- expert GEMM: OUT[n][:] = X[n][:] @ W(expert(n)); X rows grouped by expert ----------
// 128x128 tile, BK=32, 4 waves, 2-phase double-buffered global_load_lds staging.
template <int OUTF32>
__global__ __launch_bounds__(256) void gemm_exp(const u16* __restrict__ X,
                                                const u16* __restrict__ WTall,
                                                int tensor0,
                                                void* __restrict__ o0,
                                                void* __restrict__ o1,
                                                void* __restrict__ o2,
                                                const int* __restrict__ cntp) {
  const int z = blockIdx.z;
  const int e = blockIdx.y >> 4;
  const int mt = blockIdx.y & 15;
  const int c0 = cntp[0];
  const int lo = e ? c0 : 0;
  const int hi = e ? N_TOK : c0;
  const int rb = mt * 128;
  if (rb >= hi || rb + 128 <= lo) return;   // tile fully outside this expert's rows
  const int cb = blockIdx.x * 128;
  void* OUT = (z == 0) ? o0 : (z == 1) ? o1 : o2;
  const u16* W = WTall + ((size_t)((tensor0 + z) * 2 + e) << 20);

  const int tid = threadIdx.x;
  const int w = tid >> 6, l = tid & 63, lg = l >> 4, ln = l & 15;
  const int wm = (w >> 1) * 64, wn = (w & 1) * 64;

  __shared__ __align__(16) char smem[32768];  // 2 bufs x (A 8K + B 8K)

  auto stage = [&](int it, int b_) {
    const int k0b = it * 64;                 // 32 bf16 = 64 bytes per row
    #pragma unroll
    for (int c = 0; c < 2; ++c) {
      const int lb = (tid + c * 256) * 16;
      const int row = lb >> 6, colb = lb & 63;
      g2l16((const char*)X + (size_t)(rb + row) * 2048 + k0b + colb,
            &smem[b_ * 16384 + lb]);
      g2l16((const char*)W + (size_t)(cb + row) * 2048 + k0b + colb,
            &smem[b_ * 16384 + 8192 + lb]);
    }
  };

  f32x4 acc[4][4];
  #pragma unroll
  for (int i = 0; i < 4; ++i)
    #pragma unroll
    for (int j = 0; j < 4; ++j) acc[i][j] = (f32x4){0.f, 0.f, 0.f, 0.f};

  stage(0, 0);
  __syncthreads();
  for (int it = 0; it < 32; ++it) {
    const int b_ = it & 1;
    if (it < 31) stage(it + 1, b_ ^ 1);
    short8v a[4], bb[4];
    #pragma unroll
    for (int mi = 0; mi < 4; ++mi)
      a[mi] = *(const short8v*)&smem[b_ * 16384 + (wm + mi * 16 + ln) * 64 + lg * 16];
    #pragma unroll
    for (int ni = 0; ni < 4; ++ni)
      bb[ni] = *(const short8v*)&smem[b_ * 16384 + 8192 + (wn + ni * 16 + ln) * 64 + lg * 16];
    #pragma unroll
    for (int mi = 0; mi < 4; ++mi)
      #pragma unroll
      for (int ni = 0; ni < 4; ++ni)
        acc[mi][ni] = MFMA(a[mi], bb[ni], acc[mi][ni], 0, 0, 0);
    __syncthreads();  // waits vmcnt(0) too -> next buffer staged
  }

  #pragma unroll
  for (int mi = 0; mi < 4; ++mi) {
    #pragma unroll
    for (int r = 0; r < 4; ++r) {
      const int row = rb + wm + mi * 16 + lg * 4 + r;
      if (row >= lo && row < hi) {
        #pragma unroll
        for (int ni = 0; ni < 4; ++ni) {
          const int col = cb + wn + ni * 16 + ln;
          if (OUTF32) ((float*)OUT)[(size_t)row * DIM + col] = acc[mi][ni][r];
          else ((u16*)OUT)[(size_t)row * DIM + col] = f2b(acc[mi][ni][r]);
        }
      }
    }
  }
}

// ---------- flash attention: grid (32 qtiles, 16 heads), 4 waves x 16 q-rows ----------
__global__ __launch_bounds__(256) void attn_fwd(const u16* __restrict__ qg,
                                                const u16* __restrict__ kg,
                                                const u16* __restrict__ vTg,
                                                u16* __restrict__ og) {
  const int qt = blockIdx.x, h = blockIdx.y;
  const int tid = threadIdx.x, w = tid >> 6, l = tid & 63, lg = l >> 4, ln = l & 15;
  // LDS: Q[0,8K) K0[8K,16K) K1[16K,24K) V0[24K,32K) V1[32K,40K) P[40K, +4*2304)
  __shared__ __align__(16) char smem[50176];
  const int PB = 40960 + w * 2304;           // per-wave P: 16 rows x 144 B (64+8 bf16 pad)

  auto stageKV = [&](int kt_, int b_) {
    const char* kb = (const char*)kg + ((size_t)kt_ * 64) * 2048 + h * 128;
    const char* vb = (const char*)vTg + ((size_t)h * HD) * 4096 + (size_t)kt_ * 128;
    #pragma unroll
    for (int c = 0; c < 2; ++c) {
      const int lb = (tid + c * 256) * 16;
      const int row = lb >> 7;
      const int col = (lb & 127) ^ ((row & 7) << 4);   // pre-swizzled source (T2 both-sides)
      g2l16(kb + (size_t)row * 2048 + col, &smem[8192 + b_ * 8192 + lb]);
      g2l16(vb + (size_t)row * 4096 + col, &smem[24576 + b_ * 8192 + lb]);
    }
  };
  auto ldf = [&](int base, int row, int colb) -> short8v {
    return *(const short8v*)&smem[base + row * 128 + (colb ^ ((row & 7) << 4))];
  };

  { // prologue: Q + tile 0
    const char* qb = (const char*)qg + ((size_t)qt * 64) * 2048 + h * 128;
    #pragma unroll
    for (int c = 0; c < 2; ++c) {
      const int lb = (tid + c * 256) * 16;
      const int row = lb >> 7;
      const int col = (lb & 127) ^ ((row & 7) << 4);
      g2l16(qb + (size_t)row * 2048 + col, &smem[lb]);
    }
    stageKV(0, 0);
  }
  __syncthreads();

  const short8v qf0 = ldf(0, w * 16 + ln, lg * 16);
  const short8v qf1 = ldf(0, w * 16 + ln, lg * 16 + 64);

  float m_s[4], l_s[4];
  f32x4 accO[4];
  #pragma unroll
  for (int r = 0; r < 4; ++r) { m_s[r] = -3e38f; l_s[r] = 0.f; }
  #pragma unroll
  for (int hf = 0; hf < 4; ++hf) accO[hf] = (f32x4){0.f, 0.f, 0.f, 0.f};

  for (int kt = 0; kt < 32; ++kt) {
    const int b_ = kt & 1;
    if (kt < 31) stageKV(kt + 1, b_ ^ 1);

    // S = Q K^T (per wave: 16 q x 64 keys)
    f32x4 sv[4];
    #pragma unroll
    for (int nf = 0; nf < 4; ++nf) {
      short8v k0 = ldf(8192 + b_ * 8192, nf * 16 + ln, lg * 16);
      short8v k1 = ldf(8192 + b_ * 8192, nf * 16 + ln, lg * 16 + 64);
      f32x4 zz = (f32x4){0.f, 0.f, 0.f, 0.f};
      zz = MFMA(qf0, k0, zz, 0, 0, 0);
      zz = MFMA(qf1, k1, zz, 0, 0, 0);
      sv[nf] = zz;
    }
    // online softmax (rows live in 16-lane groups; reg r = q-row lg*4+r)
    float p[4][4], mx[4];
    #pragma unroll
    for (int r = 0; r < 4; ++r) mx[r] = -3e38f;
    #pragma unroll
    for (int nf = 0; nf < 4; ++nf)
      #pragma unroll
      for (int r = 0; r < 4; ++r) {
        float t = sv[nf][r] * 0.125f;
        p[nf][r] = t;
        mx[r] = fmaxf(mx[r], t);
      }
    #pragma unroll
    for (int off = 1; off < 16; off <<= 1)
      #pragma unroll
      for (int r = 0; r < 4; ++r) mx[r] = fmaxf(mx[r], __shfl_xor(mx[r], off, 16));
    float alpha[4], rs[4];
    #pragma unroll
    for (int r = 0; r < 4; ++r) {
      float mn = fmaxf(m_s[r], mx[r]);
      alpha[r] = __expf(m_s[r] - mn);
      m_s[r] = mn;
      rs[r] = 0.f;
    }
    #pragma unroll
    for (int nf = 0; nf < 4; ++nf)
      #pragma unroll
      for (int r = 0; r < 4; ++r) {
        u16 pb = f2b(__expf(p[nf][r] - m_s[r]));
        rs[r] += b2f(pb);  // denominator from the rounded P for consistency
        *(u16*)&smem[PB + (lg * 4 + r) * 144 + (ln + nf * 16) * 2] = pb;
      }
    #pragma unroll
    for (int off = 1; off < 16; off <<= 1)
      #pragma unroll
      for (int r = 0; r < 4; ++r) rs[r] += __shfl_xor(rs[r], off, 16);
    #pragma unroll
    for (int r = 0; r < 4; ++r) l_s[r] = l_s[r] * alpha[r] + rs[r];
    #pragma unroll
    for (int hf = 0; hf < 4; ++hf)
      #pragma unroll
      for (int r = 0; r < 4; ++r) accO[hf][r] *= alpha[r];

    // O += P V  (A = P from per-wave LDS, B = V^T tile)
    #pragma unroll
    for (int ks = 0; ks < 2; ++ks) {
      short8v pa = *(const short8v*)&smem[PB + ln * 144 + lg * 16 + ks * 64];
      #pragma unroll
      for (int hf = 0; hf < 4; ++hf) {
        short8v vb = ldf(24576 + b_ * 8192, hf * 16 + ln, lg * 16 + ks * 64);
        accO[hf] = MFMA(pa, vb, accO[hf], 0, 0, 0);
      }
    }
    __syncthreads();
  }

  #pragma unroll
  for (int hf = 0; hf < 4; ++hf)
    #pragma unroll
    for (int r = 0; r < 4; ++r) {
      const int row = qt * 64 + w * 16 + lg * 4 + r;
      og[(size_t)row * DIM + h * HD + hf * 16 + ln] = f2b(accO[hf][r] / l_s[r]);
    }
}

// ---------- LayerNorm + per-modality affine + scatter to original order ----------
__global__ __launch_bounds__(256) void ln_scatter(const float* __restrict__ o,
                                                  const float* __restrict__ lnw,
                                                  const float* __restrict__ lnb,
                                                  const int* __restrict__ perm,
                                                  const int* __restrict__ cntp,
                                                  float* __restrict__ out) {
  const int i = blockIdx.x;
  const int tid = threadIdx.x, w = tid >> 6, l = tid & 63;
  const int mod = (i < cntp[0]) ? 0 : 1;
  float4 v = ((const float4*)(o + (size_t)i * DIM))[tid];
  float s = v.x + v.y + v.z + v.w;
  float ss = v.x * v.x + v.y * v.y + v.z * v.z + v.w * v.w;
  #pragma unroll
  for (int off = 1; off < 64; off <<= 1) {
    s += __shfl_xor(s, off, 64);
    ss += __shfl_xor(ss, off, 64);
  }
  __shared__ float rs4[4], rss4[4];
  if (l == 0) { rs4[w] = s; rss4[w] = ss; }
  __syncthreads();
  const float st = rs4[0] + rs4[1] + rs4[2] + rs4[3];
  const float sst = rss4[0] + rss4[1] + rss4[2] + rss4[3];
  const float mu = st * (1.f / DIM);
  const float var = sst * (1.f / DIM) - mu * mu;
  const float rstd = rsqrtf(var + 1e-5f);
  const int drow = perm[i];
  float4 g = ((const float4*)(lnw + (size_t)mod * DIM))[tid];
  float4 b = ((const float4*)(lnb + (size_t)mod * DIM))[tid];
  float4 rr;
  rr.x = (v.x - mu) * rstd * g.x + b.x;
  rr.y = (v.y - mu) * rstd * g.y + b.y;
  rr.z = (v.z - mu) * rstd * g.z + b.z;
  rr.w = (v.w - mu) * rstd * g.w + b.w;
  ((float4*)(out + (size_t)drow * DIM))[tid] = rr;
}

// ---------- launch ----------
extern "C" void kernel_launch(void* const* d_in, const int* in_sizes, int n_in,
                              void* d_out, int out_size, void* d_ws, size_t ws_size,
                              hipStream_t stream) {
  const float* x = (const float*)d_in[0];
  const void* masks = d_in[1];
  const float* wq = (const float*)d_in[3];
  const float* wk = (const float*)d_in[4];
  const float* wv = (const float*)d_in[5];
  const float* wo = (const float*)d_in[6];
  const float* lnw = (const float*)d_in[7];
  const float* lnb = (const float*)d_in[8];

  char* ws = (char*)d_ws;
  int* perm = (int*)(ws + OFF_PERM);
  int* cnt = (int*)(ws + OFF_CNT);
  u16* xpb = (u16*)(ws + OFF_XPB);
  u16* wT = (u16*)(ws + OFF_WT);
  u16* q = (u16*)(ws + OFF_Q);
  u16* k = (u16*)(ws + OFF_K);
  u16* v = (u16*)(ws + OFF_V);
  u16* vT = (u16*)(ws + OFF_VT);
  u16* at = (u16*)(ws + OFF_AT);
  float* o = (float*)(ws + OFF_O);
  float* out = (float*)d_out;

  prep_kernel<<<1, 256, 0, stream>>>(masks, perm, cnt);
  gather_cast<<<N_TOK, 256, 0, stream>>>(x, perm, xpb);
  wcast<<<dim3(32, 32, 8), dim3(32, 8), 0, stream>>>(wq, wk, wv, wo, wT);
  gemm_exp<0><<<dim3(8, 32, 3), 256, 0, stream>>>(xpb, wT, 0, q, k, v, cnt);
  vtrans<<<dim3(64, 2, 16), dim3(32, 8), 0, stream>>>(v, vT);
  attn_fwd<<<dim3(32, 16), 256, 0, stream>>>(q, k, vT, at);
  gemm_exp<1><<<dim3(8, 32, 1), 256, 0, stream>>>(at, wT, 3, o, o, o, cnt);
  ln_scatter<<<N_TOK, 256, 0, stream>>>(o, lnw, lnb, perm, cnt, out);
}

// Round 2
// 117.640 us; speedup vs baseline: 1.2227x; 1.2227x over previous
//
#include <hip/hip_runtime.h>

typedef __attribute__((ext_vector_type(8))) short short8v;
typedef __attribute__((ext_vector_type(4))) float f32x4;
typedef unsigned short u16;
typedef unsigned int u32;

#define MFMA __builtin_amdgcn_mfma_f32_16x16x32_bf16

// ---------- helpers ----------
__device__ __forceinline__ u16 f2b(float f) {
  u32 u = __float_as_uint(f);
  u = (u + 0x7FFFu + ((u >> 16) & 1u)) >> 16;
  return (u16)u;
}
__device__ __forceinline__ float b2f(u16 b) {
  return __uint_as_float(((u32)b) << 16);
}
__device__ __forceinline__ void g2l16(const void* g, void* l) {
  __builtin_amdgcn_global_load_lds(
      (const __attribute__((address_space(1))) unsigned int*)g,
      (__attribute__((address_space(3))) unsigned int*)l, 16, 0, 0);
}

// sizes
#define N_TOK 2048
#define DIM 1024
#define NH 16
#define HD 64

// Q pre-scale: hd^-0.5 * log2(e)  (softmax runs in exp2 domain)
#define QSCALE 0.18033688011112042f

// workspace layout (bytes)
#define OFF_PERM 0
#define OFF_CNT 8192
#define OFF_XPB 16384
#define OFF_WT (OFF_XPB + 4194304)          // 16 MB: [tensor][expert][1024][1024] bf16, WT[n][k]
#define OFF_Q (OFF_WT + 16777216)
#define OFF_K (OFF_Q + 4194304)
#define OFF_V (OFF_K + 4194304)
#define OFF_VT (OFF_V + 4194304)            // [16][64][2048] bf16
#define OFF_AT (OFF_VT + 4194304)
#define OFF_O (OFF_AT + 4194304)            // f32 [2048][1024]

// ---------- prep: modality ids, stable partition perm, cnt0 ----------
__global__ __launch_bounds__(256) void prep_kernel(const void* __restrict__ masks,
                                                   int* __restrict__ perm,
                                                   int* __restrict__ cnt) {
  const int tid = threadIdx.x;
  __shared__ u32 red[256];
  __shared__ int scan[256];
  const u32* mw = (const u32*)masks;
  u32 mx = 0;
  for (int i = tid; i < 1024; i += 256) { u32 v = mw[i]; mx = mx > v ? mx : v; }
  red[tid] = mx;
  __syncthreads();
  for (int off = 128; off; off >>= 1) {
    if (tid < off) red[tid] = red[tid] > red[tid + off] ? red[tid] : red[tid + off];
    __syncthreads();
  }
  const bool isbyte = red[0] > 1u;
  int md[8];
  int c0loc = 0;
  #pragma unroll
  for (int j = 0; j < 8; ++j) {
    const int n = tid * 8 + j;
    int m1;
    if (isbyte) m1 = ((const unsigned char*)masks)[N_TOK + n] != 0;
    else        m1 = mw[N_TOK + n] != 0;
    md[j] = m1;
    c0loc += (m1 == 0);
  }
  scan[tid] = c0loc;
  __syncthreads();
  for (int off = 1; off < 256; off <<= 1) {
    int v = (tid >= off) ? scan[tid - off] : 0;
    __syncthreads();
    scan[tid] += v;
    __syncthreads();
  }
  const int incl = scan[tid];
  const int total0 = scan[255];
  const int excl0 = incl - c0loc;
  int p0 = excl0;
  int p1 = total0 + (tid * 8 - excl0);
  #pragma unroll
  for (int j = 0; j < 8; ++j) {
    const int n = tid * 8 + j;
    if (!md[j]) perm[p0++] = n; else perm[p1++] = n;
  }
  if (tid == 0) cnt[0] = total0;
}

// ---------- gather + cast x -> xp bf16 ----------
__global__ __launch_bounds__(256) void gather_cast(const float* __restrict__ x,
                                                   const int* __restrict__ perm,
                                                   u16* __restrict__ xpb) {
  const int i = blockIdx.x;
  const int src = perm[i];
  const int tid = threadIdx.x;
  float4 v = ((const float4*)(x + (size_t)src * DIM))[tid];
  ushort4 o;
  o.x = f2b(v.x); o.y = f2b(v.y); o.z = f2b(v.z); o.w = f2b(v.w);
  ((ushort4*)(xpb + (size_t)i * DIM))[tid] = o;
}

// ---------- weight transpose-cast: W[k][n] f32 -> WT[n][k] bf16 ----------
__global__ __launch_bounds__(256) void wcast(const float* __restrict__ wq,
                                             const float* __restrict__ wk,
                                             const float* __restrict__ wv,
                                             const float* __restrict__ wo,
                                             u16* __restrict__ wT) {
  const int mat = blockIdx.z;               // tensor*2 + expert
  const int tensor = mat >> 1, expert = mat & 1;
  const float* src = (tensor == 0) ? wq : (tensor == 1) ? wk : (tensor == 2) ? wv : wo;
  src += (size_t)expert * (1 << 20);
  u16* dst = wT + ((size_t)mat << 20);
  const int k0 = blockIdx.x * 32, n0 = blockIdx.y * 32;
  const int tx = threadIdx.x, ty = threadIdx.y;
  __shared__ float t[32][33];
  #pragma unroll
  for (int r = 0; r < 4; ++r)
    t[ty + 8 * r][tx] = src[(size_t)(k0 + ty + 8 * r) * DIM + n0 + tx];
  __syncthreads();
  #pragma unroll
  for (int r = 0; r < 4; ++r)
    dst[(size_t)(n0 + ty + 8 * r) * DIM + k0 + tx] = f2b(t[tx][ty + 8 * r]);
}

// ---------- V transpose per head: v[n][h*64+d] -> vT[h][d][n] ----------
__global__ __launch_bounds__(256) void vtrans(const u16* __restrict__ v,
                                              u16* __restrict__ vT) {
  const int h = blockIdx.z;
  const int n0 = blockIdx.x * 32, d0 = blockIdx.y * 32;
  const int tx = threadIdx.x, ty = threadIdx.y;
  __shared__ u16 t[32][33];
  #pragma unroll
  for (int r = 0; r < 4; ++r)
    t[ty + 8 * r][tx] = v[(size_t)(n0 + ty + 8 * r) * DIM + h * HD + d0 + tx];
  __syncthreads();
  #pragma unroll
  for (int r = 0; r < 4; ++r)
    vT[(size_t)(h * HD + d0 + ty + 8 * r) * N_TOK + n0 + tx] = t[tx][ty + 8 * r];
}

// ---------- expert GEMM ----------
template <int OUTF32>
__global__ __launch_bounds__(256) void gemm_exp(const u16* __restrict__ X,
                                                const u16* __restrict__ WTall,
                                                int tensor0, float scale0,
                                                void* __restrict__ o0,
                                                void* __restrict__ o1,
                                                void* __restrict__ o2,
                                                const int* __restrict__ cntp) {
  const int z = blockIdx.z;
  const int e = blockIdx.y >> 4;
  const int mt = blockIdx.y & 15;
  const int c0 = cntp[0];
  const int lo = e ? c0 : 0;
  const int hi = e ? N_TOK : c0;
  const int rb = mt * 128;
  if (rb >= hi || rb + 128 <= lo) return;
  const int cb = blockIdx.x * 128;
  void* OUT = (z == 0) ? o0 : (z == 1) ? o1 : o2;
  const u16* W = WTall + ((size_t)((tensor0 + z) * 2 + e) << 20);
  const float scl = (z == 0) ? scale0 : 1.f;

  const int tid = threadIdx.x;
  const int w = tid >> 6, l = tid & 63, lg = l >> 4, ln = l & 15;
  const int wm = (w >> 1) * 64, wn = (w & 1) * 64;

  __shared__ __align__(16) char smem[32768];

  auto stage = [&](int it, int b_) {
    const int k0b = it * 64;
    #pragma unroll
    for (int c = 0; c < 2; ++c) {
      const int lb = (tid + c * 256) * 16;
      const int row = lb >> 6, colb = lb & 63;
      g2l16((const char*)X + (size_t)(rb + row) * 2048 + k0b + colb,
            &smem[b_ * 16384 + lb]);
      g2l16((const char*)W + (size_t)(cb + row) * 2048 + k0b + colb,
            &smem[b_ * 16384 + 8192 + lb]);
    }
  };

  f32x4 acc[4][4];
  #pragma unroll
  for (int i = 0; i < 4; ++i)
    #pragma unroll
    for (int j = 0; j < 4; ++j) acc[i][j] = (f32x4){0.f, 0.f, 0.f, 0.f};

  stage(0, 0);
  __syncthreads();
  for (int it = 0; it < 32; ++it) {
    const int b_ = it & 1;
    if (it < 31) stage(it + 1, b_ ^ 1);
    short8v a[4], bb[4];
    #pragma unroll
    for (int mi = 0; mi < 4; ++mi)
      a[mi] = *(const short8v*)&smem[b_ * 16384 + (wm + mi * 16 + ln) * 64 + lg * 16];
    #pragma unroll
    for (int ni = 0; ni < 4; ++ni)
      bb[ni] = *(const short8v*)&smem[b_ * 16384 + 8192 + (wn + ni * 16 + ln) * 64 + lg * 16];
    __builtin_amdgcn_s_setprio(1);
    #pragma unroll
    for (int mi = 0; mi < 4; ++mi)
      #pragma unroll
      for (int ni = 0; ni < 4; ++ni)
        acc[mi][ni] = MFMA(a[mi], bb[ni], acc[mi][ni], 0, 0, 0);
    __builtin_amdgcn_s_setprio(0);
    __syncthreads();
  }

  #pragma unroll
  for (int mi = 0; mi < 4; ++mi) {
    #pragma unroll
    for (int r = 0; r < 4; ++r) {
      const int row = rb + wm + mi * 16 + lg * 4 + r;
      if (row >= lo && row < hi) {
        #pragma unroll
        for (int ni = 0; ni < 4; ++ni) {
          const int col = cb + wn + ni * 16 + ln;
          const float vv = acc[mi][ni][r] * scl;
          if (OUTF32) ((float*)OUT)[(size_t)row * DIM + col] = vv;
          else ((u16*)OUT)[(size_t)row * DIM + col] = f2b(vv);
        }
      }
    }
  }
}

// ---------- flash attention, swapped-QK^T per-lane softmax ----------
// grid (32 qtiles, 16 heads), 4 waves x 16 q-rows. Q pre-scaled by QSCALE.
__global__ __launch_bounds__(256) void attn_fwd(const u16* __restrict__ qg,
                                                const u16* __restrict__ kg,
                                                const u16* __restrict__ vTg,
                                                u16* __restrict__ og) {
  const int qt = blockIdx.x, h = blockIdx.y;
  const int tid = threadIdx.x, w = tid >> 6, l = tid & 63, lg = l >> 4, ln = l & 15;
  const int e_ = (ln & 7) ^ (ln >> 3);       // 16B-slot swizzle key for P row = ln
  // LDS: K dbuf [0,16K) | V dbuf [16K,32K) | P 4 x 2048 [32K,40K)
  __shared__ __align__(16) char smem[40960];
  const int PB = 32768 + w * 2048;

  auto esw = [](int row) { return (((row & 7) ^ ((row >> 3) & 1)) << 4); };

  auto stageKV = [&](int kt_, int b_) {
    const char* kb = (const char*)kg + ((size_t)kt_ * 64) * 2048 + h * 128;
    const char* vb = (const char*)vTg + ((size_t)h * HD) * 4096 + (size_t)kt_ * 128;
    #pragma unroll
    for (int c = 0; c < 2; ++c) {
      const int lb = (tid + c * 256) * 16;
      const int row = lb >> 7;
      const int col = (lb & 127) ^ esw(row);   // pre-swizzled source (both-sides rule)
      g2l16(kb + (size_t)row * 2048 + col, &smem[b_ * 8192 + lb]);
      g2l16(vb + (size_t)row * 4096 + col, &smem[16384 + b_ * 8192 + lb]);
    }
  };
  auto ldf = [&](int base, int row, int colb) -> short8v {
    return *(const short8v*)&smem[base + row * 128 + (colb ^ esw(row))];
  };

  // Q fragments from global (B-operand: lane's q-col = ln)
  const char* qrow = (const char*)qg + ((size_t)(qt * 64 + w * 16 + ln)) * 2048 + h * 128;
  const short8v qf0 = *(const short8v*)(qrow + lg * 16);
  const short8v qf1 = *(const short8v*)(qrow + lg * 16 + 64);

  stageKV(0, 0);
  __syncthreads();

  float m_s = -3e38f, l_s = 0.f;
  f32x4 accO[4];
  #pragma unroll
  for (int hf = 0; hf < 4; ++hf) accO[hf] = (f32x4){0.f, 0.f, 0.f, 0.f};

  for (int kt = 0; kt < 32; ++kt) {
    const int b_ = kt & 1;
    if (kt < 31) stageKV(kt + 1, b_ ^ 1);

    // S^T = K·Q^T : lane holds S[key = 16nf+4lg+r][q = ln]  (exp2 domain)
    f32x4 sv[4];
    #pragma unroll
    for (int nf = 0; nf < 4; ++nf) {
      short8v k0 = ldf(b_ * 8192, nf * 16 + ln, lg * 16);
      short8v k1 = ldf(b_ * 8192, nf * 16 + ln, lg * 16 + 64);
      f32x4 zz = (f32x4){0.f, 0.f, 0.f, 0.f};
      __builtin_amdgcn_s_setprio(1);
      zz = MFMA(k0, qf0, zz, 0, 0, 0);
      zz = MFMA(k1, qf1, zz, 0, 0, 0);
      __builtin_amdgcn_s_setprio(0);
      sv[nf] = zz;
    }

    // per-lane tile max (16 in-lane values), then reduce over lg (lanes ^16, ^32)
    float tmax = sv[0][0];
    #pragma unroll
    for (int nf = 0; nf < 4; ++nf)
      #pragma unroll
      for (int r = 0; r < 4; ++r) tmax = fmaxf(tmax, sv[nf][r]);
    tmax = fmaxf(tmax, __shfl_xor(tmax, 16, 64));
    tmax = fmaxf(tmax, __shfl_xor(tmax, 32, 64));

    // defer-max (T13): rescale only when tile max grows past THR (exp2 domain)
    if (!__all(tmax <= m_s + 11.0f)) {
      const float mn = fmaxf(m_s, tmax);
      const float alpha = __builtin_amdgcn_exp2f(m_s - mn);
      m_s = mn;
      l_s *= alpha;
      float ar[4];
      #pragma unroll
      for (int r = 0; r < 4; ++r) ar[r] = __shfl(alpha, lg * 4 + r, 16);
      #pragma unroll
      for (int hf = 0; hf < 4; ++hf)
        #pragma unroll
        for (int r = 0; r < 4; ++r) accO[hf][r] *= ar[r];
    }

    // P = exp2(S - m): cvt_pk pairs -> 4x ds_write_b64 into swizzled P row
    float rs = 0.f;
    #pragma unroll
    for (int nf = 0; nf < 4; ++nf) {
      const float p0 = __builtin_amdgcn_exp2f(sv[nf][0] - m_s);
      const float p1 = __builtin_amdgcn_exp2f(sv[nf][1] - m_s);
      const float p2 = __builtin_amdgcn_exp2f(sv[nf][2] - m_s);
      const float p3 = __builtin_amdgcn_exp2f(sv[nf][3] - m_s);
      rs += (p0 + p1) + (p2 + p3);
      u32 pk0, pk1;
      asm("v_cvt_pk_bf16_f32 %0, %1, %2" : "=v"(pk0) : "v"(p0), "v"(p1));
      asm("v_cvt_pk_bf16_f32 %0, %1, %2" : "=v"(pk1) : "v"(p2), "v"(p3));
      const int slot = 2 * nf + (lg >> 1);
      *(uint2*)&smem[PB + ln * 128 + (((slot ^ e_) << 4) | ((lg & 1) << 3))] =
          make_uint2(pk0, pk1);
    }
    rs += __shfl_xor(rs, 16, 64);
    rs += __shfl_xor(rs, 32, 64);
    l_s += rs;

    // O += P V   (A = P row ln from per-wave LDS, B = V^T tile)
    #pragma unroll
    for (int ks = 0; ks < 2; ++ks) {
      short8v pa = *(const short8v*)&smem[PB + ln * 128 + (((4 * ks + lg) ^ e_) << 4)];
      __builtin_amdgcn_s_setprio(1);
      #pragma unroll
      for (int hf = 0; hf < 4; ++hf) {
        short8v vb = ldf(16384 + b_ * 8192, hf * 16 + ln, lg * 16 + ks * 64);
        accO[hf] = MFMA(pa, vb, accO[hf], 0, 0, 0);
      }
      __builtin_amdgcn_s_setprio(0);
    }
    __syncthreads();
  }

  float lr[4];
  #pragma unroll
  for (int r = 0; r < 4; ++r) lr[r] = 1.f / __shfl(l_s, lg * 4 + r, 16);
  #pragma unroll
  for (int hf = 0; hf < 4; ++hf)
    #pragma unroll
    for (int r = 0; r < 4; ++r) {
      const int row = qt * 64 + w * 16 + lg * 4 + r;
      og[(size_t)row * DIM + h * HD + hf * 16 + ln] = f2b(accO[hf][r] * lr[r]);
    }
}

// ---------- LayerNorm + per-modality affine + scatter ----------
__global__ __launch_bounds__(256) void ln_scatter(const float* __restrict__ o,
                                                  const float* __restrict__ lnw,
                                                  const float* __restrict__ lnb,
                                                  const int* __restrict__ perm,
                                                  const int* __restrict__ cntp,
                                                  float* __restrict__ out) {
  const int i = blockIdx.x;
  const int tid = threadIdx.x, w = tid >> 6, l = tid & 63;
  const int mod = (i < cntp[0]) ? 0 : 1;
  float4 v = ((const float4*)(o + (size_t)i * DIM))[tid];
  float s = v.x + v.y + v.z + v.w;
  float ss = v.x * v.x + v.y * v.y + v.z * v.z + v.w * v.w;
  #pragma unroll
  for (int off = 1; off < 64; off <<= 1) {
    s += __shfl_xor(s, off, 64);
    ss += __shfl_xor(ss, off, 64);
  }
  __shared__ float rs4[4], rss4[4];
  if (l == 0) { rs4[w] = s; rss4[w] = ss; }
  __syncthreads();
  const float st = rs4[0] + rs4[1] + rs4[2] + rs4[3];
  const float sst = rss4[0] + rss4[1] + rss4[2] + rss4[3];
  const float mu = st * (1.f / DIM);
  const float var = sst * (1.f / DIM) - mu * mu;
  const float rstd = rsqrtf(var + 1e-5f);
  const int drow = perm[i];
  float4 g = ((const float4*)(lnw + (size_t)mod * DIM))[tid];
  float4 b = ((const float4*)(lnb + (size_t)mod * DIM))[tid];
  float4 rr;
  rr.x = (v.x - mu) * rstd * g.x + b.x;
  rr.y = (v.y - mu) * rstd * g.y + b.y;
  rr.z = (v.z - mu) * rstd * g.z + b.z;
  rr.w = (v.w - mu) * rstd * g.w + b.w;
  ((float4*)(out + (size_t)drow * DIM))[tid] = rr;
}

// ---------- launch ----------
extern "C" void kernel_launch(void* const* d_in, const int* in_sizes, int n_in,
                              void* d_out, int out_size, void* d_ws, size_t ws_size,
                              hipStream_t stream) {
  const float* x = (const float*)d_in[0];
  const void* masks = d_in[1];
  const float* wq = (const float*)d_in[3];
  const float* wk = (const float*)d_in[4];
  const float* wv = (const float*)d_in[5];
  const float* wo = (const float*)d_in[6];
  const float* lnw = (const float*)d_in[7];
  const float* lnb = (const float*)d_in[8];

  char* ws = (char*)d_ws;
  int* perm = (int*)(ws + OFF_PERM);
  int* cnt = (int*)(ws + OFF_CNT);
  u16* xpb = (u16*)(ws + OFF_XPB);
  u16* wT = (u16*)(ws + OFF_WT);
  u16* q = (u16*)(ws + OFF_Q);
  u16* k = (u16*)(ws + OFF_K);
  u16* v = (u16*)(ws + OFF_V);
  u16* vT = (u16*)(ws + OFF_VT);
  u16* at = (u16*)(ws + OFF_AT);
  float* o = (float*)(ws + OFF_O);
  float* out = (float*)d_out;

  prep_kernel<<<1, 256, 0, stream>>>(masks, perm, cnt);
  gather_cast<<<N_TOK, 256, 0, stream>>>(x, perm, xpb);
  wcast<<<dim3(32, 32, 8), dim3(32, 8), 0, stream>>>(wq, wk, wv, wo, wT);
  gemm_exp<0><<<dim3(8, 32, 3), 256, 0, stream>>>(xpb, wT, 0, QSCALE, q, k, v, cnt);
  vtrans<<<dim3(64, 2, 16), dim3(32, 8), 0, stream>>>(v, vT);
  attn_fwd<<<dim3(32, 16), 256, 0, stream>>>(q, k, vT, at);
  gemm_exp<1><<<dim3(8, 32, 1), 256, 0, stream>>>(at, wT, 3, 1.0f, o, o, o, cnt);
  ln_scatter<<<N_TOK, 256, 0, stream>>>(o, lnw, lnb, perm, cnt, out);
}

// Round 3
// 111.025 us; speedup vs baseline: 1.2956x; 1.0596x over previous
//
#include <hip/hip_runtime.h>

typedef __attribute__((ext_vector_type(8))) short short8v;
typedef __attribute__((ext_vector_type(4))) float f32x4;
typedef __attribute__((ext_vector_type(16))) float f32x16;
typedef unsigned short u16;
typedef unsigned int u32;

#define MFMA __builtin_amdgcn_mfma_f32_16x16x32_bf16
#define MFMA32 __builtin_amdgcn_mfma_f32_32x32x16_bf16

// ---------- helpers ----------
__device__ __forceinline__ u16 f2b(float f) {
  u32 u = __float_as_uint(f);
  u = (u + 0x7FFFu + ((u >> 16) & 1u)) >> 16;
  return (u16)u;
}
__device__ __forceinline__ float b2f(u16 b) {
  return __uint_as_float(((u32)b) << 16);
}
__device__ __forceinline__ void g2l16(const void* g, void* l) {
  __builtin_amdgcn_global_load_lds(
      (const __attribute__((address_space(1))) unsigned int*)g,
      (__attribute__((address_space(3))) unsigned int*)l, 16, 0, 0);
}

// sizes
#define N_TOK 2048
#define DIM 1024
#define NH 16
#define HD 64

// Q pre-scale: hd^-0.5 * log2(e)  (softmax runs in exp2 domain)
#define QSCALE 0.18033688011112042f

// workspace layout (bytes)
#define OFF_PERM 0
#define OFF_CNT 8192
#define OFF_XPB 16384
#define OFF_WT (OFF_XPB + 4194304)          // 16 MB: [tensor][expert][1024][1024] bf16, WT[n][k]
#define OFF_Q (OFF_WT + 16777216)
#define OFF_K (OFF_Q + 4194304)
#define OFF_V (OFF_K + 4194304)
#define OFF_VT (OFF_V + 4194304)            // [16][64][2048] bf16
#define OFF_AT (OFF_VT + 4194304)
#define OFF_O (OFF_AT + 4194304)            // f32 [2048][1024]

// ---------- prep: modality ids, stable partition perm, cnt0 ----------
__global__ __launch_bounds__(256) void prep_kernel(const void* __restrict__ masks,
                                                   int* __restrict__ perm,
                                                   int* __restrict__ cnt) {
  const int tid = threadIdx.x;
  __shared__ u32 red[256];
  __shared__ int scan[256];
  const u32* mw = (const u32*)masks;
  u32 mx = 0;
  for (int i = tid; i < 1024; i += 256) { u32 v = mw[i]; mx = mx > v ? mx : v; }
  red[tid] = mx;
  __syncthreads();
  for (int off = 128; off; off >>= 1) {
    if (tid < off) red[tid] = red[tid] > red[tid + off] ? red[tid] : red[tid + off];
    __syncthreads();
  }
  const bool isbyte = red[0] > 1u;
  int md[8];
  int c0loc = 0;
  #pragma unroll
  for (int j = 0; j < 8; ++j) {
    const int n = tid * 8 + j;
    int m1;
    if (isbyte) m1 = ((const unsigned char*)masks)[N_TOK + n] != 0;
    else        m1 = mw[N_TOK + n] != 0;
    md[j] = m1;
    c0loc += (m1 == 0);
  }
  scan[tid] = c0loc;
  __syncthreads();
  for (int off = 1; off < 256; off <<= 1) {
    int v = (tid >= off) ? scan[tid - off] : 0;
    __syncthreads();
    scan[tid] += v;
    __syncthreads();
  }
  const int incl = scan[tid];
  const int total0 = scan[255];
  const int excl0 = incl - c0loc;
  int p0 = excl0;
  int p1 = total0 + (tid * 8 - excl0);
  #pragma unroll
  for (int j = 0; j < 8; ++j) {
    const int n = tid * 8 + j;
    if (!md[j]) perm[p0++] = n; else perm[p1++] = n;
  }
  if (tid == 0) cnt[0] = total0;
}

// ---------- gather + cast x -> xp bf16 ----------
__global__ __launch_bounds__(256) void gather_cast(const float* __restrict__ x,
                                                   const int* __restrict__ perm,
                                                   u16* __restrict__ xpb) {
  const int i = blockIdx.x;
  const int src = perm[i];
  const int tid = threadIdx.x;
  float4 v = ((const float4*)(x + (size_t)src * DIM))[tid];
  ushort4 o;
  o.x = f2b(v.x); o.y = f2b(v.y); o.z = f2b(v.z); o.w = f2b(v.w);
  ((ushort4*)(xpb + (size_t)i * DIM))[tid] = o;
}

// ---------- weight transpose-cast: W[k][n] f32 -> WT[n][k] bf16 ----------
__global__ __launch_bounds__(256) void wcast(const float* __restrict__ wq,
                                             const float* __restrict__ wk,
                                             const float* __restrict__ wv,
                                             const float* __restrict__ wo,
                                             u16* __restrict__ wT) {
  const int mat = blockIdx.z;               // tensor*2 + expert
  const int tensor = mat >> 1, expert = mat & 1;
  const float* src = (tensor == 0) ? wq : (tensor == 1) ? wk : (tensor == 2) ? wv : wo;
  src += (size_t)expert * (1 << 20);
  u16* dst = wT + ((size_t)mat << 20);
  const int k0 = blockIdx.x * 32, n0 = blockIdx.y * 32;
  const int tx = threadIdx.x, ty = threadIdx.y;
  __shared__ float t[32][33];
  #pragma unroll
  for (int r = 0; r < 4; ++r)
    t[ty + 8 * r][tx] = src[(size_t)(k0 + ty + 8 * r) * DIM + n0 + tx];
  __syncthreads();
  #pragma unroll
  for (int r = 0; r < 4; ++r)
    dst[(size_t)(n0 + ty + 8 * r) * DIM + k0 + tx] = f2b(t[tx][ty + 8 * r]);
}

// ---------- V transpose per head: v[n][h*64+d] -> vT[h][d][n] ----------
__global__ __launch_bounds__(256) void vtrans(const u16* __restrict__ v,
                                              u16* __restrict__ vT) {
  const int h = blockIdx.z;
  const int n0 = blockIdx.x * 32, d0 = blockIdx.y * 32;
  const int tx = threadIdx.x, ty = threadIdx.y;
  __shared__ u16 t[32][33];
  #pragma unroll
  for (int r = 0; r < 4; ++r)
    t[ty + 8 * r][tx] = v[(size_t)(n0 + ty + 8 * r) * DIM + h * HD + d0 + tx];
  __syncthreads();
  #pragma unroll
  for (int r = 0; r < 4; ++r)
    vT[(size_t)(h * HD + d0 + ty + 8 * r) * N_TOK + n0 + tx] = t[tx][ty + 8 * r];
}

// ---------- expert GEMM ----------
template <int OUTF32>
__global__ __launch_bounds__(256) void gemm_exp(const u16* __restrict__ X,
                                                const u16* __restrict__ WTall,
                                                int tensor0, float scale0,
                                                void* __restrict__ o0,
                                                void* __restrict__ o1,
                                                void* __restrict__ o2,
                                                const int* __restrict__ cntp) {
  const int z = blockIdx.z;
  const int e = blockIdx.y >> 4;
  const int mt = blockIdx.y & 15;
  const int c0 = cntp[0];
  const int lo = e ? c0 : 0;
  const int hi = e ? N_TOK : c0;
  const int rb = mt * 128;
  if (rb >= hi || rb + 128 <= lo) return;
  const int cb = blockIdx.x * 128;
  void* OUT = (z == 0) ? o0 : (z == 1) ? o1 : o2;
  const u16* W = WTall + ((size_t)((tensor0 + z) * 2 + e) << 20);
  const float scl = (z == 0) ? scale0 : 1.f;

  const int tid = threadIdx.x;
  const int w = tid >> 6, l = tid & 63, lg = l >> 4, ln = l & 15;
  const int wm = (w >> 1) * 64, wn = (w & 1) * 64;

  __shared__ __align__(16) char smem[32768];

  auto stage = [&](int it, int b_) {
    const int k0b = it * 64;
    #pragma unroll
    for (int c = 0; c < 2; ++c) {
      const int lb = (tid + c * 256) * 16;
      const int row = lb >> 6, colb = lb & 63;
      g2l16((const char*)X + (size_t)(rb + row) * 2048 + k0b + colb,
            &smem[b_ * 16384 + lb]);
      g2l16((const char*)W + (size_t)(cb + row) * 2048 + k0b + colb,
            &smem[b_ * 16384 + 8192 + lb]);
    }
  };

  f32x4 acc[4][4];
  #pragma unroll
  for (int i = 0; i < 4; ++i)
    #pragma unroll
    for (int j = 0; j < 4; ++j) acc[i][j] = (f32x4){0.f, 0.f, 0.f, 0.f};

  stage(0, 0);
  __syncthreads();
  for (int it = 0; it < 32; ++it) {
    const int b_ = it & 1;
    if (it < 31) stage(it + 1, b_ ^ 1);
    short8v a[4], bb[4];
    #pragma unroll
    for (int mi = 0; mi < 4; ++mi)
      a[mi] = *(const short8v*)&smem[b_ * 16384 + (wm + mi * 16 + ln) * 64 + lg * 16];
    #pragma unroll
    for (int ni = 0; ni < 4; ++ni)
      bb[ni] = *(const short8v*)&smem[b_ * 16384 + 8192 + (wn + ni * 16 + ln) * 64 + lg * 16];
    __builtin_amdgcn_s_setprio(1);
    #pragma unroll
    for (int mi = 0; mi < 4; ++mi)
      #pragma unroll
      for (int ni = 0; ni < 4; ++ni)
        acc[mi][ni] = MFMA(a[mi], bb[ni], acc[mi][ni], 0, 0, 0);
    __builtin_amdgcn_s_setprio(0);
    __syncthreads();
  }

  #pragma unroll
  for (int mi = 0; mi < 4; ++mi) {
    #pragma unroll
    for (int r = 0; r < 4; ++r) {
      const int row = rb + wm + mi * 16 + lg * 4 + r;
      if (row >= lo && row < hi) {
        #pragma unroll
        for (int ni = 0; ni < 4; ++ni) {
          const int col = cb + wn + ni * 16 + ln;
          const float vv = acc[mi][ni][r] * scl;
          if (OUTF32) ((float*)OUT)[(size_t)row * DIM + col] = vv;
          else ((u16*)OUT)[(size_t)row * DIM + col] = f2b(vv);
        }
      }
    }
  }
}

// ---------- flash attention: 32x32x16 MFMA, in-register P, split-K ----------
// grid (32 qtiles, 16 heads); block = 4 waves: wave w -> qgrp g=w&1 (32 q rows),
// key-half kh=w>>1 (1024 keys, 16 iters of KVBLK=64). End merge via LDS.
__global__ __launch_bounds__(256, 2) void attn_fwd(const u16* __restrict__ qg,
                                                   const u16* __restrict__ kg,
                                                   const u16* __restrict__ vTg,
                                                   u16* __restrict__ og) {
  const int qt = blockIdx.x, h = blockIdx.y;
  const int tid = threadIdx.x, w = tid >> 6, l = tid & 63;
  const int g = w & 1, kh = w >> 1;
  const int q31 = l & 31;                    // this lane's q (in S^T) / d (in O)
  const int hi = l >> 5;                     // lane half
  const int hi16 = hi * 16, hi4 = hi * 4;

  // LDS: stream s (=kh): [s*32768 + b*16384): K 8KB | V 8KB.  Merge reuses
  // [0,16384) for Obuf and [32768,+1KB) for m/l (both free after last iter).
  __shared__ __align__(16) char smem[65536];

  // ---- staging: 2 streams x (K 8KB + V 8KB) per iter, 8 chunks/thread ----
  auto stage = [&](int it, int b_) {
    #pragma unroll
    for (int c = 0; c < 8; ++c) {
      const int j = tid + c * 256;           // 0..2047
      const int s_ = j >> 10;                // stream (key-half)
      const int rem = j & 1023;
      const int isV = rem >> 9;
      const int cc = rem & 511;
      const int r = cc >> 3, c16 = cc & 7;
      const int colb = (c16 * 16) ^ ((r & 7) << 4);   // pre-swizzled source
      const char* src;
      if (isV)
        src = (const char*)vTg + (size_t)(h * HD + r) * 4096 + (s_ * 1024 + it * 64) * 2 + colb;
      else
        src = (const char*)kg + (size_t)(s_ * 1024 + it * 64 + r) * 2048 + h * 128 + colb;
      g2l16(src, &smem[s_ * 32768 + b_ * 16384 + isV * 8192 + cc * 16]);
    }
  };
  auto ldf = [&](int base, int row, int colb) -> short8v {
    return *(const short8v*)&smem[base + row * 128 + (colb ^ ((row & 7) << 4))];
  };

  // ---- Q fragments (B-operand): lane q-col = q31, k = hi*8+j per 16-k step ----
  const char* qrow = (const char*)qg + ((size_t)(qt * 64 + g * 32 + q31)) * 2048 + h * 128;
  short8v qf[4];
  #pragma unroll
  for (int t = 0; t < 4; ++t) qf[t] = *(const short8v*)(qrow + t * 32 + hi16);

  stage(0, 0);
  __syncthreads();

  float m_s = -1e30f, l_s = 0.f;
  f32x16 accO[2];
  #pragma unroll
  for (int dt = 0; dt < 2; ++dt)
    #pragma unroll
    for (int r = 0; r < 16; ++r) accO[dt][r] = 0.f;

  for (int it = 0; it < 16; ++it) {
    const int b_ = it & 1;
    if (it < 15) stage(it + 1, b_ ^ 1);
    const int Kb = kh * 32768 + b_ * 16384;
    const int Vb = Kb + 8192;

    #pragma unroll
    for (int ks = 0; ks < 2; ++ks) {         // 32-key subtiles
      // S^T = K Q^T : lane holds S[key=(r&3)+8(r>>2)+4hi][q=q31] (exp2 domain)
      f32x16 s_;
      #pragma unroll
      for (int r = 0; r < 16; ++r) s_[r] = 0.f;
      {
        short8v kf0 = ldf(Kb, ks * 32 + q31, 0 * 32 + hi16);
        short8v kf1 = ldf(Kb, ks * 32 + q31, 1 * 32 + hi16);
        short8v kf2 = ldf(Kb, ks * 32 + q31, 2 * 32 + hi16);
        short8v kf3 = ldf(Kb, ks * 32 + q31, 3 * 32 + hi16);
        __builtin_amdgcn_s_setprio(1);
        s_ = MFMA32(kf0, qf[0], s_, 0, 0, 0);
        s_ = MFMA32(kf1, qf[1], s_, 0, 0, 0);
        s_ = MFMA32(kf2, qf[2], s_, 0, 0, 0);
        s_ = MFMA32(kf3, qf[3], s_, 0, 0, 0);
        __builtin_amdgcn_s_setprio(0);
      }

      // tile max over this lane's 16 + partner half (same q)
      float tmax = s_[0];
      #pragma unroll
      for (int r = 1; r < 16; ++r) tmax = fmaxf(tmax, s_[r]);
      tmax = fmaxf(tmax, __shfl_xor(tmax, 32, 64));

      if (!__all(tmax <= m_s + 11.0f)) {     // defer-max (T13)
        const float mn = fmaxf(m_s, tmax);
        const float al = __builtin_amdgcn_exp2f(m_s - mn);
        m_s = mn;
        l_s *= al;
        #pragma unroll
        for (int r = 0; r < 16; ++r) {
          const float ar = __shfl(al, (r & 3) + 8 * (r >> 2) + hi4, 64);
          accO[0][r] *= ar;
          accO[1][r] *= ar;
        }
      }

      // P = exp2(S - m); pack to bf16 A-frags entirely in registers (T12)
      float p[16];
      float rs = 0.f;
      #pragma unroll
      for (int r = 0; r < 16; ++r) {
        p[r] = __builtin_amdgcn_exp2f(s_[r] - m_s);
        rs += p[r];
      }
      rs += __shfl_xor(rs, 32, 64);
      l_s += rs;

      u32 c0, c1, c2, c3, c4, c5, c6, c7;
      asm("v_cvt_pk_bf16_f32 %0, %1, %2" : "=v"(c0) : "v"(p[0]), "v"(p[1]));
      asm("v_cvt_pk_bf16_f32 %0, %1, %2" : "=v"(c1) : "v"(p[2]), "v"(p[3]));
      asm("v_cvt_pk_bf16_f32 %0, %1, %2" : "=v"(c2) : "v"(p[4]), "v"(p[5]));
      asm("v_cvt_pk_bf16_f32 %0, %1, %2" : "=v"(c3) : "v"(p[6]), "v"(p[7]));
      asm("v_cvt_pk_bf16_f32 %0, %1, %2" : "=v"(c4) : "v"(p[8]), "v"(p[9]));
      asm("v_cvt_pk_bf16_f32 %0, %1, %2" : "=v"(c5) : "v"(p[10]), "v"(p[11]));
      asm("v_cvt_pk_bf16_f32 %0, %1, %2" : "=v"(c6) : "v"(p[12]), "v"(p[13]));
      asm("v_cvt_pk_bf16_f32 %0, %1, %2" : "=v"(c7) : "v"(p[14]), "v"(p[15]));
      // swap hi-half(a) <-> lo-half(b): builds A dwords for both lane halves
      asm volatile("v_permlane32_swap_b32 %0, %1" : "+v"(c0), "+v"(c2));
      asm volatile("v_permlane32_swap_b32 %0, %1" : "+v"(c1), "+v"(c3));
      asm volatile("v_permlane32_swap_b32 %0, %1" : "+v"(c4), "+v"(c6));
      asm volatile("v_permlane32_swap_b32 %0, %1" : "+v"(c5), "+v"(c7));
      union { u32 u[4]; short8v s; } pa0, pa1;
      pa0.u[0] = c0; pa0.u[1] = c1; pa0.u[2] = c2; pa0.u[3] = c3;
      pa1.u[0] = c4; pa1.u[1] = c5; pa1.u[2] = c6; pa1.u[3] = c7;

      // O += P V : B = V^T tile rows d, cols keys
      #pragma unroll
      for (int kk = 0; kk < 2; ++kk) {
        const short8v pa = kk ? pa1.s : pa0.s;
        short8v vb0 = ldf(Vb, q31, ks * 64 + kk * 32 + hi16);
        short8v vb1 = ldf(Vb, 32 + q31, ks * 64 + kk * 32 + hi16);
        __builtin_amdgcn_s_setprio(1);
        accO[0] = MFMA32(pa, vb0, accO[0], 0, 0, 0);
        accO[1] = MFMA32(pa, vb1, accO[1], 0, 0, 0);
        __builtin_amdgcn_s_setprio(0);
      }
    }
    __syncthreads();
  }

  // ---- split-K merge: exchange (m,l), then alpha-scaled O add via LDS ----
  float* mlds = (float*)&smem[32768];        // m: [g*2+kh][32], l at +128 floats
  if (l < 32) {
    mlds[(g * 2 + kh) * 32 + l] = m_s;
    mlds[128 + (g * 2 + kh) * 32 + l] = l_s;
  }
  __syncthreads();
  const float m0 = mlds[(g * 2 + 0) * 32 + q31];
  const float m1 = mlds[(g * 2 + 1) * 32 + q31];
  const float l0 = mlds[128 + (g * 2 + 0) * 32 + q31];
  const float l1 = mlds[128 + (g * 2 + 1) * 32 + q31];
  const float M = fmaxf(m0, m1);
  const float a0 = __builtin_amdgcn_exp2f(m0 - M);
  const float a1 = __builtin_amdgcn_exp2f(m1 - M);
  const float linv = 1.f / (l0 * a0 + l1 * a1);
  const float aown = kh ? a1 : a0;
  float* obuf = (float*)&smem[0];            // [g][32 q][64 d]
  if (kh == 1) {
    #pragma unroll
    for (int r = 0; r < 16; ++r) {
      const int qr = (r & 3) + 8 * (r >> 2) + hi4;
      const float ar = __shfl(aown, qr, 64);
      obuf[(g * 32 + qr) * 64 + q31] = accO[0][r] * ar;
      obuf[(g * 32 + qr) * 64 + 32 + q31] = accO[1][r] * ar;
    }
  }
  __syncthreads();
  if (kh == 0) {
    #pragma unroll
    for (int r = 0; r < 16; ++r) {
      const int qr = (r & 3) + 8 * (r >> 2) + hi4;
      const float ar = __shfl(aown, qr, 64);
      const float li = __shfl(linv, qr, 64);
      const int row = qt * 64 + g * 32 + qr;
      const float v0 = (accO[0][r] * ar + obuf[(g * 32 + qr) * 64 + q31]) * li;
      const float v1 = (accO[1][r] * ar + obuf[(g * 32 + qr) * 64 + 32 + q31]) * li;
      og[(size_t)row * DIM + h * HD + q31] = f2b(v0);
      og[(size_t)row * DIM + h * HD + 32 + q31] = f2b(v1);
    }
  }
}

// ---------- LayerNorm + per-modality affine + scatter ----------
__global__ __launch_bounds__(256) void ln_scatter(const float* __restrict__ o,
                                                  const float* __restrict__ lnw,
                                                  const float* __restrict__ lnb,
                                                  const int* __restrict__ perm,
                                                  const int* __restrict__ cntp,
                                                  float* __restrict__ out) {
  const int i = blockIdx.x;
  const int tid = threadIdx.x, w = tid >> 6, l = tid & 63;
  const int mod = (i < cntp[0]) ? 0 : 1;
  float4 v = ((const float4*)(o + (size_t)i * DIM))[tid];
  float s = v.x + v.y + v.z + v.w;
  float ss = v.x * v.x + v.y * v.y + v.z * v.z + v.w * v.w;
  #pragma unroll
  for (int off = 1; off < 64; off <<= 1) {
    s += __shfl_xor(s, off, 64);
    ss += __shfl_xor(ss, off, 64);
  }
  __shared__ float rs4[4], rss4[4];
  if (l == 0) { rs4[w] = s; rss4[w] = ss; }
  __syncthreads();
  const float st = rs4[0] + rs4[1] + rs4[2] + rs4[3];
  const float sst = rss4[0] + rss4[1] + rss4[2] + rss4[3];
  const float mu = st * (1.f / DIM);
  const float var = sst * (1.f / DIM) - mu * mu;
  const float rstd = rsqrtf(var + 1e-5f);
  const int drow = perm[i];
  float4 g = ((const float4*)(lnw + (size_t)mod * DIM))[tid];
  float4 b = ((const float4*)(lnb + (size_t)mod * DIM))[tid];
  float4 rr;
  rr.x = (v.x - mu) * rstd * g.x + b.x;
  rr.y = (v.y - mu) * rstd * g.y + b.y;
  rr.z = (v.z - mu) * rstd * g.z + b.z;
  rr.w = (v.w - mu) * rstd * g.w + b.w;
  ((float4*)(out + (size_t)drow * DIM))[tid] = rr;
}

// ---------- launch ----------
extern "C" void kernel_launch(void* const* d_in, const int* in_sizes, int n_in,
                              void* d_out, int out_size, void* d_ws, size_t ws_size,
                              hipStream_t stream) {
  const float* x = (const float*)d_in[0];
  const void* masks = d_in[1];
  const float* wq = (const float*)d_in[3];
  const float* wk = (const float*)d_in[4];
  const float* wv = (const float*)d_in[5];
  const float* wo = (const float*)d_in[6];
  const float* lnw = (const float*)d_in[7];
  const float* lnb = (const float*)d_in[8];

  char* ws = (char*)d_ws;
  int* perm = (int*)(ws + OFF_PERM);
  int* cnt = (int*)(ws + OFF_CNT);
  u16* xpb = (u16*)(ws + OFF_XPB);
  u16* wT = (u16*)(ws + OFF_WT);
  u16* q = (u16*)(ws + OFF_Q);
  u16* k = (u16*)(ws + OFF_K);
  u16* v = (u16*)(ws + OFF_V);
  u16* vT = (u16*)(ws + OFF_VT);
  u16* at = (u16*)(ws + OFF_AT);
  float* o = (float*)(ws + OFF_O);
  float* out = (float*)d_out;

  prep_kernel<<<1, 256, 0, stream>>>(masks, perm, cnt);
  gather_cast<<<N_TOK, 256, 0, stream>>>(x, perm, xpb);
  wcast<<<dim3(32, 32, 8), dim3(32, 8), 0, stream>>>(wq, wk, wv, wo, wT);
  gemm_exp<0><<<dim3(8, 32, 3), 256, 0, stream>>>(xpb, wT, 0, QSCALE, q, k, v, cnt);
  vtrans<<<dim3(64, 2, 16), dim3(32, 8), 0, stream>>>(v, vT);
  attn_fwd<<<dim3(32, 16), 256, 0, stream>>>(q, k, vT, at);
  gemm_exp<1><<<dim3(8, 32, 1), 256, 0, stream>>>(at, wT, 3, 1.0f, o, o, o, cnt);
  ln_scatter<<<N_TOK, 256, 0, stream>>>(o, lnw, lnb, perm, cnt, out);
}